// Round 3
// baseline (47.164 us; speedup 1.0000x reference)
//
#include <hip/hip_runtime.h>
#include <math.h>

// N=512, IN_F=128, OUT_F=64, H=4.
// e_raw[i,j,h] = s1[i][j>>7][h] + s2[j][h]
//   s1[i][g][h] = dot(ht[i][g*64:], a[h][:64]) ; s2[j][h] = dot(ht[j][h*64:], a[h][64:])
// leaky_relu(0.2) -> *ew -> mask adj -> softmax over j
// c[i][h*64+f] = sum_j alpha[i,j,h]*ht[j][h*64+f] ; out = sigmoid(h U^T + c V^T)

__device__ __forceinline__ float wave_sum(float v) {
    #pragma unroll
    for (int o = 32; o; o >>= 1) v += __shfl_xor(v, o, 64);
    return v;
}
__device__ __forceinline__ float wave_max(float v) {
    #pragma unroll
    for (int o = 32; o; o >>= 1) v = fmaxf(v, __shfl_xor(v, o, 64));
    return v;
}

// ---------------- K1: ht = h @ W^T, plus s1, s2 ----------------
// 256 blocks x 512 thr, 2 rows/block, 1 output/thread.
__global__ __launch_bounds__(512) void k_transform(
    const float* __restrict__ h, const float* __restrict__ W,
    const float* __restrict__ a,
    float* __restrict__ ht, float* __restrict__ s1, float* __restrict__ s2p)
{
    __shared__ float hsh[2 * 128];
    __shared__ float ash[512];      // a[4][128]
    __shared__ float hts[2 * 256];  // this block's ht rows
    const int t = threadIdx.x;
    const int i0 = blockIdx.x * 2;
    if (t < 64)       ((float4*)hsh)[t]      = ((const float4*)(h + i0 * 128))[t];
    else if (t < 192) ((float4*)ash)[t - 64] = ((const float4*)a)[t - 64];
    __syncthreads();

    const int r = t >> 8, col = t & 255;
    float acc = 0.f;
    const float4* Wv = (const float4*)(W + col * 128);
    const float* hp = hsh + r * 128;
    #pragma unroll
    for (int kk = 0; kk < 32; ++kk) {
        float4 w4 = Wv[kk];
        acc += w4.x * hp[kk*4] + w4.y * hp[kk*4+1] + w4.z * hp[kk*4+2] + w4.w * hp[kk*4+3];
    }
    ht[(i0 + r) * 256 + col] = acc;
    hts[r * 256 + col] = acc;
    __syncthreads();

    // 40 small dots: t<40, rr=t&1, o=t>>1. o<16: s1; o>=16: s2.
    if (t < 40) {
        const int rr = t & 1, o = t >> 1;
        const float* x;
        const float* y;
        if (o < 16) { x = hts + rr * 256 + (o >> 2) * 64;  y = ash + (o & 3) * 128; }
        else        { x = hts + rr * 256 + (o - 16) * 64;  y = ash + (o - 16) * 128 + 64; }
        const int st = (t << 3) & 63;   // bank stagger
        float s0 = 0.f, sA = 0.f, sB = 0.f, sC = 0.f;
        #pragma unroll
        for (int ff = 0; ff < 64; ff += 4) {
            int f0 = (st + ff) & 63, f1 = (st + ff + 1) & 63,
                f2 = (st + ff + 2) & 63, f3 = (st + ff + 3) & 63;
            s0 += x[f0] * y[f0];  sA += x[f1] * y[f1];
            sB += x[f2] * y[f2];  sC += x[f3] * y[f3];
        }
        float s = (s0 + sA) + (sB + sC);
        if (o < 16) s1[(i0 + rr) * 16 + (o >> 2) * 4 + (o & 3)] = s;
        else        s2p[(o - 16) * 512 + i0 + rr] = s;
    }
}

__device__ __forceinline__ float sc(float e, float w, int ad) {
    e = (e >= 0.f) ? e : 0.2f * e;
    e *= w;
    return (ad > 0) ? e : -9.0e15f;
}

// ---------------- K2: attention + aggregate ----------------
// 256 blocks (64 i-tiles x 4 heads) x 512 thr (8 waves).
__global__ __launch_bounds__(512) void k_att(
    const int* __restrict__ adj, const float* __restrict__ ew,
    const float* __restrict__ ht, const float* __restrict__ s1,
    const float* __restrict__ s2p, float* __restrict__ c)
{
    __shared__ float att[8 * 512];   // raw exp -> (reused) partial-c
    __shared__ float s1sh[32];
    __shared__ float s2sh[512];
    const int t = threadIdx.x;
    const int hh = blockIdx.x & 3;
    const int i0 = (blockIdx.x >> 2) * 8;

    s2sh[t] = s2p[hh * 512 + t];
    if (t < 32) s1sh[t] = s1[(i0 + (t >> 2)) * 16 + (t & 3) * 4 + hh];
    __syncthreads();

    // scores: thread = (row r, 8 consecutive j), vectorized loads
    const int r = t >> 6;
    const int j0 = (t & 63) * 8;
    {
        const float s1v = s1sh[r * 4 + (j0 >> 7)];
        #pragma unroll
        for (int q = 0; q < 2; ++q) {
            const int jq = j0 + q * 4;
            int4   av = *(const int4*)  (adj + (i0 + r) * 512 + jq);
            float4 wv = *(const float4*)(ew  + (i0 + r) * 512 + jq);
            float4 sv = *(const float4*)&s2sh[jq];
            float4 o;
            o.x = sc(s1v + sv.x, wv.x, av.x);
            o.y = sc(s1v + sv.y, wv.y, av.y);
            o.z = sc(s1v + sv.z, wv.z, av.z);
            o.w = sc(s1v + sv.w, wv.w, av.w);
            *(float4*)&att[r * 512 + jq] = o;
        }
    }
    __syncthreads();

    // softmax row w in registers; store RAW exp, defer 1/sum to the end
    const int w = t >> 6, lane = t & 63;
    float inv;
    {
        float v[8];
        #pragma unroll
        for (int k = 0; k < 8; ++k) v[k] = att[w * 512 + k * 64 + lane];
        float m = v[0];
        #pragma unroll
        for (int k = 1; k < 8; ++k) m = fmaxf(m, v[k]);
        m = wave_max(m);
        float s = 0.f;
        #pragma unroll
        for (int k = 0; k < 8; ++k) { v[k] = __expf(v[k] - m); s += v[k]; }
        s = wave_sum(s);
        inv = 1.f / s;
        #pragma unroll
        for (int k = 0; k < 8; ++k) att[w * 512 + k * 64 + lane] = v[k];
    }
    __syncthreads();

    // aggregate: wave w covers j in [w*64, w*64+64) for all 8 rows
    float pacc[8] = {0.f, 0.f, 0.f, 0.f, 0.f, 0.f, 0.f, 0.f};
    const float* htp = ht + hh * 64 + lane;
    const int jbase = w * 64;
    #pragma unroll 4
    for (int jj = 0; jj < 64; jj += 4) {
        const int j = jbase + jj;
        float hv0 = htp[(j + 0) * 256];
        float hv1 = htp[(j + 1) * 256];
        float hv2 = htp[(j + 2) * 256];
        float hv3 = htp[(j + 3) * 256];
        #pragma unroll
        for (int rr = 0; rr < 8; ++rr) {
            float4 ar = *(const float4*)&att[rr * 512 + j];  // LDS broadcast
            pacc[rr] += ar.x * hv0 + ar.y * hv1 + ar.z * hv2 + ar.w * hv3;
        }
    }
    __syncthreads();
    #pragma unroll
    for (int rr = 0; rr < 8; ++rr) att[w * 512 + rr * 64 + lane] = pacc[rr];
    __syncthreads();
    float s = 0.f;
    #pragma unroll
    for (int v8 = 0; v8 < 8; ++v8) s += att[v8 * 512 + w * 64 + lane];
    c[(i0 + w) * 256 + hh * 64 + lane] = s * inv;   // wave w owns row w's inv
}

// ---------------- K3: out = sigmoid(h U^T + c V^T) ----------------
// 256 blocks (128 row-tiles x 2 col-halves) x 512 thr, 4 rows x 128 cols.
__global__ __launch_bounds__(512) void k_out(
    const float* __restrict__ h, const float* __restrict__ cbuf,
    const float* __restrict__ U, const float* __restrict__ V,
    float* __restrict__ out)
{
    __shared__ float hsh[4 * 128];
    __shared__ float csh[4 * 256];
    const int t = threadIdx.x;
    const int i0 = (blockIdx.x >> 1) * 4;
    const int ch = blockIdx.x & 1;
    if (t < 128)      ((float4*)hsh)[t]       = ((const float4*)(h + i0 * 128))[t];
    else if (t < 384) ((float4*)csh)[t - 128] = ((const float4*)(cbuf + i0 * 256))[t - 128];
    __syncthreads();

    const int r = t >> 7, col = (t & 127) + ch * 128;
    float acc = 0.f;
    const float4* Uv = (const float4*)(U + col * 128);
    const float* hp = hsh + r * 128;
    #pragma unroll
    for (int kk = 0; kk < 32; ++kk) {
        float4 u4 = Uv[kk];
        acc += u4.x * hp[kk*4] + u4.y * hp[kk*4+1] + u4.z * hp[kk*4+2] + u4.w * hp[kk*4+3];
    }
    const float4* Vv = (const float4*)(V + col * 256);
    const float* cp = csh + r * 256;
    #pragma unroll
    for (int kk = 0; kk < 64; ++kk) {
        float4 v4 = Vv[kk];
        acc += v4.x * cp[kk*4] + v4.y * cp[kk*4+1] + v4.z * cp[kk*4+2] + v4.w * cp[kk*4+3];
    }
    out[(i0 + r) * 256 + col] = 1.f / (1.f + __expf(-acc));
}

extern "C" void kernel_launch(void* const* d_in, const int* in_sizes, int n_in,
                              void* d_out, int out_size, void* d_ws, size_t ws_size,
                              hipStream_t stream) {
    const float* h   = (const float*)d_in[0];
    const int*   adj = (const int*)d_in[1];
    const float* ew  = (const float*)d_in[2];
    const float* W   = (const float*)d_in[3];
    const float* a   = (const float*)d_in[4];
    const float* U   = (const float*)d_in[5];
    const float* V   = (const float*)d_in[6];
    float* out = (float*)d_out;

    float* ht  = (float*)d_ws;           // 512*256
    float* s1  = ht + 512 * 256;         // 512*16
    float* s2p = s1 + 512 * 16;          // 4*512
    float* c   = s2p + 4 * 512;          // 512*256

    k_transform<<<256, 512, 0, stream>>>(h, W, a, ht, s1, s2p);
    k_att<<<256, 512, 0, stream>>>(adj, ew, ht, s1, s2p, c);
    k_out<<<256, 512, 0, stream>>>(h, c, U, V, out);
}